// Round 14
// baseline (226.316 us; speedup 1.0000x reference)
//
#include <hip/hip_runtime.h>

typedef __bf16 bf16x8 __attribute__((ext_vector_type(8)));
typedef float  f32x4  __attribute__((ext_vector_type(4)));

#define LOG2E 1.4426950408889634f

static __device__ __forceinline__ float fexp2(float x) { return __builtin_amdgcn_exp2f(x); }
static __device__ __forceinline__ float frcp(float x)  { return __builtin_amdgcn_rcpf(x); }
static __device__ __forceinline__ float fsigmoid(float x) { return frcp(1.0f + fexp2(-LOG2E * x)); }
static __device__ __forceinline__ float ftanh(float x)    { return 2.0f * frcp(1.0f + fexp2(-2.0f * LOG2E * x)) - 1.0f; }

// ---------------------------------------------------------------------------
// Prep (verified r10-r13): pack 4 [512x512] fp32 weights into bf16 16x16x32
// B-fragment order, GATE-CONTIGUOUS:
// Wp[(((cn*16+ks)*4+g)*64 + lt)*8 + e] = W_g[cn*16+(lt&15)][ks*32+(lt>>4)*8+e]
// Per cn: 64 KiB; per (cn,ks): 4 KiB = 4 gates x 1 KiB, lane-linear.
// ---------------------------------------------------------------------------
__global__ __launch_bounds__(256) void wpack(const float* __restrict__ Wf,
                                             const float* __restrict__ Wi,
                                             const float* __restrict__ Wg,
                                             const float* __restrict__ Wo,
                                             __bf16* __restrict__ Wp)
{
    int idx = blockIdx.x * 256 + threadIdx.x;      // [0, 131072)
    int kg  = idx & 63;                            // k-group of 8
    int j   = (idx >> 6) & 511;                    // weight row = output col
    int g   = idx >> 15;
    const float* src = (g == 0) ? Wf : (g == 1) ? Wi : (g == 2) ? Wg : Wo;
    const float4* s4 = (const float4*)(src + j * 512 + kg * 8);
    float4 v0 = s4[0], v1 = s4[1];
    bf16x8 o;
    o[0] = (__bf16)v0.x; o[1] = (__bf16)v0.y; o[2] = (__bf16)v0.z; o[3] = (__bf16)v0.w;
    o[4] = (__bf16)v1.x; o[5] = (__bf16)v1.y; o[6] = (__bf16)v1.z; o[7] = (__bf16)v1.w;
    int cn = j >> 4;                               // 16-col group
    int ks = kg >> 2;                              // K=32 step
    int lt = (j & 15) + (kg & 3) * 16;             // lane slot
    size_t dst = ((size_t)(((cn * 16 + ks) * 4 + g) * 64 + lt)) * 8;
    *(bf16x8*)(Wp + dst) = o;
}

// ---------------------------------------------------------------------------
// Wave-specialized main kernel. 1024 blocks x BM=64. 512 thr = 8 waves:
// waves 0-3 = PRODUCERS (K-loop, MFMA, zero global stores -> clean vmcnt,
// inline-asm 2-deep B pipeline with counted vmcnt(4)); waves 4-7 = CONSUMERS
// (poll LDS ring, transcendentals, all global stores). One producer +
// one consumer per SIMD -> MFMA pipe and VALU/store path overlap.
// LDS: 64K z-image + 4 pairs x 5 slots x 4K ring + flags = 147 KiB.
// ---------------------------------------------------------------------------
__global__ __launch_bounds__(512, 2) void lstm_main(
    const float* __restrict__ xin, const float* __restrict__ stm,
    const __bf16* __restrict__ Wp,
    const float* __restrict__ bfv, const float* __restrict__ biv,
    const float* __restrict__ bgv, const float* __restrict__ bov,
    float* __restrict__ out)
{
    __shared__ unsigned char zs[65536];            // 64 rows x 512 k, bf16, frag image
    __shared__ unsigned char ring[4][5][4096];     // [pair][slot][gate*1024 + lane*16]
    __shared__ int pflag[4];                       // chunks published (per pair)
    __shared__ int cflag[4];                       // chunks consumed  (per pair)
    const int tid  = threadIdx.x;
    const int lane = tid & 63;
    const int wv   = tid >> 6;                     // 0..7
    const int pid  = wv & 3;                       // producer/consumer pair id
    const int l15  = lane & 15;
    const int lq   = lane >> 4;                    // 0..3
    const int row0 = blockIdx.x * 64;

    if (tid < 4) { pflag[tid] = 0; cflag[tid] = 0; }

    // ---- phase 0: z = x + stm -> bf16 -> LDS frag image (verified r5), all 8 waves ----
    {
        const float* xb = xin + (size_t)row0 * 512;
        const float* sb = stm + (size_t)row0 * 512;
        #pragma unroll
        for (int it = 0; it < 8; ++it) {
            int idx = it * 512 + tid;              // [0, 4096): 64 rows x 64 kgroups
            int row = idx >> 6;
            int kg  = idx & 63;
            const float4* x4 = (const float4*)(xb + row * 512 + kg * 8);
            const float4* s4 = (const float4*)(sb + row * 512 + kg * 8);
            float4 a0 = x4[0], a1 = x4[1];
            float4 b0 = s4[0], b1 = s4[1];
            bf16x8 p;
            p[0] = (__bf16)(a0.x + b0.x); p[1] = (__bf16)(a0.y + b0.y);
            p[2] = (__bf16)(a0.z + b0.z); p[3] = (__bf16)(a0.w + b0.w);
            p[4] = (__bf16)(a1.x + b1.x); p[5] = (__bf16)(a1.y + b1.y);
            p[6] = (__bf16)(a1.z + b1.z); p[7] = (__bf16)(a1.w + b1.w);
            int rb   = row >> 5;                   // 0..1 chunk (32 KiB each)
            int kk   = kg >> 1;
            int slot = ((row & 31) + (kg & 1) * 32) ^ (kk & 7);
            *(bf16x8*)(zs + rb * 32768 + kk * 1024 + slot * 16) = p;
        }
    }
    __syncthreads();                               // only barrier

    volatile int* pf = (volatile int*)&pflag[pid];
    volatile int* cf = (volatile int*)&cflag[pid];

    if (wv < 4) {
        // =================== PRODUCER: K-loop, no global stores ===================
        const int kkoff = lq >> 1;                 // A-read invariants (verified r5)
        const int sl0   = l15 + (lq & 1) * 32;
        const int koffb = kkoff << 10;

#define LOADB_ASM(B0, B1, B2, B3, KS) { \
    const char* a_ = bp + (KS) * 4096; \
    asm volatile("global_load_dwordx4 %0, %4, off\n\t" \
                 "global_load_dwordx4 %1, %4, off offset:1024\n\t" \
                 "global_load_dwordx4 %2, %4, off offset:2048\n\t" \
                 "global_load_dwordx4 %3, %4, off offset:3072" \
                 : "=&v"(B0), "=&v"(B1), "=&v"(B2), "=&v"(B3) : "v"(a_) : "memory"); }
#define WAITV4 { asm volatile("s_waitcnt vmcnt(4)" ::: "memory"); __builtin_amdgcn_sched_barrier(0); }
#define WAITV0 { asm volatile("s_waitcnt vmcnt(0)" ::: "memory"); __builtin_amdgcn_sched_barrier(0); }
#define DOMFMA(B0, B1, B2, B3, KS) { \
    const int kk7_ = ((2 * (KS)) & 7) | kkoff; \
    const int t0_  = ((sl0 ^ kk7_) << 4) + (KS) * 2048 + koffb; \
    bf16x8 a0_ = *(const bf16x8*)(zs + t0_); \
    bf16x8 a1_ = *(const bf16x8*)(zs + t0_ + 256); \
    bf16x8 a2_ = *(const bf16x8*)(zs + 32768 + t0_); \
    bf16x8 a3_ = *(const bf16x8*)(zs + 32768 + t0_ + 256); \
    __builtin_amdgcn_s_setprio(1); \
    acc[0][0] = __builtin_amdgcn_mfma_f32_16x16x32_bf16(a0_, B0, acc[0][0], 0, 0, 0); \
    acc[1][0] = __builtin_amdgcn_mfma_f32_16x16x32_bf16(a1_, B0, acc[1][0], 0, 0, 0); \
    acc[2][0] = __builtin_amdgcn_mfma_f32_16x16x32_bf16(a2_, B0, acc[2][0], 0, 0, 0); \
    acc[3][0] = __builtin_amdgcn_mfma_f32_16x16x32_bf16(a3_, B0, acc[3][0], 0, 0, 0); \
    acc[0][1] = __builtin_amdgcn_mfma_f32_16x16x32_bf16(a0_, B1, acc[0][1], 0, 0, 0); \
    acc[1][1] = __builtin_amdgcn_mfma_f32_16x16x32_bf16(a1_, B1, acc[1][1], 0, 0, 0); \
    acc[2][1] = __builtin_amdgcn_mfma_f32_16x16x32_bf16(a2_, B1, acc[2][1], 0, 0, 0); \
    acc[3][1] = __builtin_amdgcn_mfma_f32_16x16x32_bf16(a3_, B1, acc[3][1], 0, 0, 0); \
    acc[0][2] = __builtin_amdgcn_mfma_f32_16x16x32_bf16(a0_, B2, acc[0][2], 0, 0, 0); \
    acc[1][2] = __builtin_amdgcn_mfma_f32_16x16x32_bf16(a1_, B2, acc[1][2], 0, 0, 0); \
    acc[2][2] = __builtin_amdgcn_mfma_f32_16x16x32_bf16(a2_, B2, acc[2][2], 0, 0, 0); \
    acc[3][2] = __builtin_amdgcn_mfma_f32_16x16x32_bf16(a3_, B2, acc[3][2], 0, 0, 0); \
    acc[0][3] = __builtin_amdgcn_mfma_f32_16x16x32_bf16(a0_, B3, acc[0][3], 0, 0, 0); \
    acc[1][3] = __builtin_amdgcn_mfma_f32_16x16x32_bf16(a1_, B3, acc[1][3], 0, 0, 0); \
    acc[2][3] = __builtin_amdgcn_mfma_f32_16x16x32_bf16(a2_, B3, acc[2][3], 0, 0, 0); \
    acc[3][3] = __builtin_amdgcn_mfma_f32_16x16x32_bf16(a3_, B3, acc[3][3], 0, 0, 0); \
    __builtin_amdgcn_s_setprio(0); }

        int slot = 0;
        for (int pass = 0; pass < 8; ++pass) {
            const int cn   = pass * 4 + pid;       // 16-col group [0,32)
            const int colj = cn * 16 + l15;
            const char* bp = (const char*)Wp + (size_t)cn * 65536 + (size_t)lane * 16;

            float bias0 = bfv[colj], bias1 = biv[colj];
            float bias2 = bgv[colj], bias3 = bov[colj];
            f32x4 acc[4][4];                       // [m][gate] = 64 regs
            #pragma unroll
            for (int m = 0; m < 4; ++m) {
                #pragma unroll
                for (int r = 0; r < 4; ++r) {
                    acc[m][0][r] = bias0; acc[m][1][r] = bias1;
                    acc[m][2][r] = bias2; acc[m][3][r] = bias3;
                }
            }

            bf16x8 p0, p1, p2, p3, q0, q1, q2, q3;
            // force bias loads drained so counted waits see only B loads
            asm volatile("s_waitcnt vmcnt(0)" ::: "memory");
            __builtin_amdgcn_sched_barrier(0);
            LOADB_ASM(p0, p1, p2, p3, 0)
            #pragma unroll
            for (int ks = 0; ks < 16; ks += 2) {
                LOADB_ASM(q0, q1, q2, q3, ks + 1)
                WAITV4
                DOMFMA(p0, p1, p2, p3, ks)
                if (ks + 2 < 16) {
                    LOADB_ASM(p0, p1, p2, p3, ks + 2)
                    WAITV4
                } else {
                    WAITV0
                }
                DOMFMA(q0, q1, q2, q3, ks + 1)
            }

            // ---- publish pre-activations to ring (lgkm only, no vmem) ----
            #pragma unroll
            for (int m = 0; m < 4; ++m) {
                int q = pass * 4 + m;
                if (q >= 5) {
                    while (*cf < q - 4) __builtin_amdgcn_s_sleep(2);
                    asm volatile("" ::: "memory");
                }
                unsigned char* sb = &ring[pid][slot][0] + lane * 16;
                *(f32x4*)(sb)        = acc[m][0];
                *(f32x4*)(sb + 1024) = acc[m][1];
                *(f32x4*)(sb + 2048) = acc[m][2];
                *(f32x4*)(sb + 3072) = acc[m][3];
                if (++slot == 5) slot = 0;
            }
            asm volatile("s_waitcnt lgkmcnt(0)" ::: "memory");
            if (lane == 0) *pf = pass * 4 + 4;
        }
#undef LOADB_ASM
#undef WAITV4
#undef WAITV0
#undef DOMFMA
    } else {
        // ============ CONSUMER: activations + all global stores ============
        int slot = 0;
        for (int q = 0; q < 32; ++q) {
            while (*pf < q + 1) __builtin_amdgcn_s_sleep(2);
            asm volatile("" ::: "memory");
            __builtin_amdgcn_sched_barrier(0);
            const unsigned char* sb = &ring[pid][slot][0] + lane * 16;
            f32x4 vF = *(const f32x4*)(sb);
            f32x4 vI = *(const f32x4*)(sb + 1024);
            f32x4 vG = *(const f32x4*)(sb + 2048);
            f32x4 vO = *(const f32x4*)(sb + 3072);

            const int pass = q >> 2, m = q & 3;
            const int cn   = pass * 4 + pid;
            const int colj = cn * 16 + l15;
            #pragma unroll
            for (int r = 0; r < 4; ++r) {
                float c = fsigmoid(vF[r]) + fsigmoid(vI[r]) * ftanh(vG[r]);
                float h = ftanh(c) * fsigmoid(vO[r]);
                int row = row0 + m * 16 + lq * 4 + r;
                int o   = row * 512 + colj;
                out[o] = c;
                out[33554432 + o] = h;             // h plane at 65536*512
            }
            asm volatile("s_waitcnt lgkmcnt(0)" ::: "memory");
            if (lane == 0) *cf = q + 1;
            if (++slot == 5) slot = 0;
        }
    }
}

extern "C" void kernel_launch(void* const* d_in, const int* in_sizes, int n_in,
                              void* d_out, int out_size, void* d_ws, size_t ws_size,
                              hipStream_t stream) {
    const float* xin = (const float*)d_in[0];
    const float* stm = (const float*)d_in[1];
    const float* Wf  = (const float*)d_in[2];
    const float* bf_ = (const float*)d_in[3];
    const float* Wi  = (const float*)d_in[4];
    const float* bi_ = (const float*)d_in[5];
    const float* Wg  = (const float*)d_in[6];
    const float* bg_ = (const float*)d_in[7];
    const float* Wo  = (const float*)d_in[8];
    const float* bo_ = (const float*)d_in[9];
    __bf16* Wp = (__bf16*)d_ws;                    // 2 MiB packed weights

    wpack<<<512, 256, 0, stream>>>(Wf, Wi, Wg, Wo, Wp);
    lstm_main<<<1024, 512, 0, stream>>>(xin, stm, Wp, bf_, bi_, bg_, bo_, (float*)d_out);
}